// Round 5
// baseline (197.843 us; speedup 1.0000x reference)
//
#include <hip/hip_runtime.h>
#include <stdint.h>

#define Bsz 16384
#define Hh  512
#define Kd  1024      // I + H
#define BM  256       // M rows per workgroup
#define BNJ 64        // j columns per workgroup (x5 gates)
#define BK  64        // K per tile
#define NT  16        // K tiles

// LDS buffer: A 32KB + B 40KB = 72KB; two buffers = 144KB
#define LDSB 73728

typedef __attribute__((ext_vector_type(8))) short bf16x8;
typedef __attribute__((ext_vector_type(4))) float f32x4;
typedef __attribute__((ext_vector_type(8))) unsigned short u16x8;

__device__ __forceinline__ unsigned short f2bf(float f) {
    union { float f; unsigned u; } v; v.f = f;
    unsigned u = v.u;
    return (unsigned short)((u + 0x7fffu + ((u >> 16) & 1u)) >> 16);
}
__device__ __forceinline__ float fast_tanh(float x) {
    float e = __expf(2.f * x);
    return (e - 1.f) / (e + 1.f);
}
__device__ __forceinline__ float fast_sigmoid(float x) {
    return 1.f / (1.f + __expf(-x));
}

// ---------------- pack A = [x | h_prev] -> bf16 [16384][1024] ----------------
__global__ void pack_A(const float* __restrict__ x, const float* __restrict__ h,
                       unsigned short* __restrict__ A) {
    const long total = (long)Bsz * Kd / 8;
    for (long i = (long)blockIdx.x * blockDim.x + threadIdx.x; i < total;
         i += (long)gridDim.x * blockDim.x) {
        long row = i >> 7;
        int  col = ((int)(i & 127)) << 3;
        const float* src = (col < 512) ? (x + row * 512 + col)
                                       : (h + row * 512 + (col - 512));
        float4 f0 = *(const float4*)(src);
        float4 f1 = *(const float4*)(src + 4);
        u16x8 o;
        o[0]=f2bf(f0.x); o[1]=f2bf(f0.y); o[2]=f2bf(f0.z); o[3]=f2bf(f0.w);
        o[4]=f2bf(f1.x); o[5]=f2bf(f1.y); o[6]=f2bf(f1.z); o[7]=f2bf(f1.w);
        *(u16x8*)(A + (i << 3)) = o;
    }
}

// ---- pack B into fragment-linear layout ----
// elem addr = jgrp*81920 + g*16384 + kt*1024 + kh*512 + l*8 + e
//  = W[g][ j = jgrp*16 + (l&15) ][ k = kt*64 + kh*32 + (l>>4)*8 + e ]
__global__ void pack_B(const float* __restrict__ Wxi, const float* __restrict__ Whi,
                       const float* __restrict__ Wxf, const float* __restrict__ Whf,
                       const float* __restrict__ Wxc, const float* __restrict__ Whc,
                       const float* __restrict__ Wxo, const float* __restrict__ Who,
                       const float* __restrict__ We,
                       const float* __restrict__ bxi, const float* __restrict__ bhi,
                       const float* __restrict__ bxf, const float* __restrict__ bhf,
                       const float* __restrict__ bxc, const float* __restrict__ bhc,
                       const float* __restrict__ bxo, const float* __restrict__ bho,
                       const float* __restrict__ be,
                       unsigned short* __restrict__ Bp, float* __restrict__ bias) {
    const long id = (long)blockIdx.x * blockDim.x + threadIdx.x;  // 327680 total
    if (id < 327680) {
        int blk = (int)(id >> 6);
        int l   = (int)(id & 63);
        int kh  = blk & 1;
        int kt  = (blk >> 1) & 15;
        int rest = blk >> 5;
        int g    = rest % 5;
        int jgrp = rest / 5;
        int j  = jgrp * 16 + (l & 15);
        int k0 = kt * 64 + kh * 32 + ((l >> 4) << 3);
        const float* src;
        if (g == 4) {
            src = We + (long)j * 1024 + k0;
        } else {
            const float* Wx = (g == 0) ? Wxi : (g == 1) ? Wxf : (g == 2) ? Wxc : Wxo;
            const float* Wh = (g == 0) ? Whi : (g == 1) ? Whf : (g == 2) ? Whc : Who;
            src = (k0 < 512) ? (Wx + (long)j * 512 + k0)
                             : (Wh + (long)j * 512 + (k0 - 512));
        }
        float4 f0 = *(const float4*)(src);
        float4 f1 = *(const float4*)(src + 4);
        u16x8 o;
        o[0]=f2bf(f0.x); o[1]=f2bf(f0.y); o[2]=f2bf(f0.z); o[3]=f2bf(f0.w);
        o[4]=f2bf(f1.x); o[5]=f2bf(f1.y); o[6]=f2bf(f1.z); o[7]=f2bf(f1.w);
        *(u16x8*)(Bp + (long)blk * 512 + l * 8) = o;
    }
    if (id < 2560) {
        int row = (int)id;
        int g = row >> 9, j = row & 511;
        float b;
        if (g == 4) b = be[j];
        else {
            const float* bx = (g == 0) ? bxi : (g == 1) ? bxf : (g == 2) ? bxc : bxo;
            const float* bh = (g == 0) ? bhi : (g == 1) ? bhf : (g == 2) ? bhc : bho;
            b = bx[j] + bh[j];
        }
        bias[row] = b;
    }
}

// ---------------- fused GEMM (5-gate), 1 barrier/tile, counted lgkm pipeline ----------------
#define GL16(g, l) __builtin_amdgcn_global_load_lds( \
    (const __attribute__((address_space(1))) unsigned int*)(g), \
    (__attribute__((address_space(3))) unsigned int*)(l), 16, 0, 0)

#define WAITVM0()  asm volatile("s_waitcnt vmcnt(0)" ::: "memory")
#define LGKM_I(n)  asm volatile("s_waitcnt lgkmcnt(" #n ")" ::: "memory")
#define LGKM(n)    LGKM_I(n)
#define BARRIER()  asm volatile("s_barrier" ::: "memory")
#define SCHED0()   __builtin_amdgcn_sched_barrier(0)

#define MF(a, b, c) __builtin_amdgcn_mfma_f32_16x16x32_bf16(a, b, c, 0, 0, 0)

// ---- LDS reads (pointer regs precomputed per buffer; imm offsets only) ----
#define RDA(KH, APTR) do { \
    afA[KH][0] = *(const bf16x8*)((APTR) + 0 * 2048); \
    afA[KH][1] = *(const bf16x8*)((APTR) + 1 * 2048); \
    afA[KH][2] = *(const bf16x8*)((APTR) + 2 * 2048); \
    afA[KH][3] = *(const bf16x8*)((APTR) + 3 * 2048); \
} while (0)

#define RDB(SET, BPTR, JF, KH) do { \
    SET[0] = *(const bf16x8*)((BPTR) + ((JF)*10 + 0 + (KH)) * 1024); \
    SET[1] = *(const bf16x8*)((BPTR) + ((JF)*10 + 2 + (KH)) * 1024); \
    SET[2] = *(const bf16x8*)((BPTR) + ((JF)*10 + 4 + (KH)) * 1024); \
    SET[3] = *(const bf16x8*)((BPTR) + ((JF)*10 + 6 + (KH)) * 1024); \
    SET[4] = *(const bf16x8*)((BPTR) + ((JF)*10 + 8 + (KH)) * 1024); \
} while (0)

// ---- staging: 4 A-chunks + 5 B-chunks per thread per tile (uniform) ----
#define SGA(SO, T) do { \
    GL16(asrc + 0 * 65536 + (T) * 64, lds_raw + (SO) + adst + 0 * 8192); \
    GL16(asrc + 1 * 65536 + (T) * 64, lds_raw + (SO) + adst + 1 * 8192); \
    GL16(asrc + 2 * 65536 + (T) * 64, lds_raw + (SO) + adst + 2 * 8192); \
    GL16(asrc + 3 * 65536 + (T) * 64, lds_raw + (SO) + adst + 3 * 8192); \
} while (0)

#define SGB(SO, T) do { \
    GL16(bstg0 + (T) * 1024, lds_raw + (SO) + bdst + 0 * 1024); \
    GL16(bstg1 + (T) * 1024, lds_raw + (SO) + bdst + 1 * 1024); \
    GL16(bstg2 + (T) * 1024, lds_raw + (SO) + bdst + 2 * 1024); \
    GL16(bstg3 + (T) * 1024, lds_raw + (SO) + bdst + 3 * 1024); \
    GL16(bstg4 + (T) * 1024, lds_raw + (SO) + bdst + 4 * 1024); \
} while (0)

#define MFMA20(KH, JF, BSET) do { \
    __builtin_amdgcn_s_setprio(1); \
    _Pragma("unroll") \
    for (int g_ = 0; g_ < 5; ++g_) { \
        acc[g_][0][JF] = MF(afA[KH][0], BSET[g_], acc[g_][0][JF]); \
        acc[g_][1][JF] = MF(afA[KH][1], BSET[g_], acc[g_][1][JF]); \
        acc[g_][2][JF] = MF(afA[KH][2], BSET[g_], acc[g_][2][JF]); \
        acc[g_][3][JF] = MF(afA[KH][3], BSET[g_], acc[g_][3][JF]); \
    } \
    __builtin_amdgcn_s_setprio(0); \
} while (0)

// One K-tile: 4 clusters x 20 MFMA, counted lgkm, 1 vmcnt + 1 barrier at end.
// APK0/APK1: A read ptrs (buf, kh); BPTR: B read ptr (buf); SO: stage buf offset.
#define TILE(APK0, APK1, BPTR, SO, T, STG, SYNC) do { \
    RDA(0, APK0); RDB(bs0, BPTR, 0, 0); SCHED0(); \
    RDB(bs1, BPTR, 1, 0); SCHED0(); \
    if (STG) { SGB(SO, (T) + 1); } SCHED0(); \
    LGKM(5); SCHED0(); \
    MFMA20(0, 0, bs0); SCHED0(); \
    RDA(1, APK1); RDB(bs0, BPTR, 0, 1); SCHED0(); \
    if (STG) { SGA(SO, (T) + 1); } SCHED0(); \
    LGKM(9); SCHED0(); \
    MFMA20(0, 1, bs1); SCHED0(); \
    RDB(bs1, BPTR, 1, 1); SCHED0(); \
    LGKM(5); SCHED0(); \
    MFMA20(1, 0, bs0); SCHED0(); \
    LGKM(0); SCHED0(); \
    MFMA20(1, 1, bs1); SCHED0(); \
    if (SYNC) { WAITVM0(); BARRIER(); } \
} while (0)

__global__ __launch_bounds__(512, 2)
void xlstm_gemm(const unsigned short* __restrict__ A,
                const unsigned short* __restrict__ Bp,
                const float* __restrict__ bias,
                const float* __restrict__ c_prev,
                float* __restrict__ out) {
    __shared__ __align__(16) unsigned char lds_raw[2 * LDSB];  // 144 KB

    const int tid  = threadIdx.x;
    const int wid  = tid >> 6;
    const int lane = tid & 63;
    const int wm   = wid >> 1;    // 0..3 : M quarter (64 rows)
    const int wj   = wid & 1;     // 0..1 : j half (32 cols -> 2 frags)
    const int fr   = lane & 15;
    const int q    = lane >> 4;

    // T1: bijective XCD swizzle (nwg = 512, 512 % 8 == 0)
    const int orig = blockIdx.x;
    const int wg   = (orig & 7) * 64 + (orig >> 3);
    const int mblk = wg >> 3;     // 0..63
    const int jblk = wg & 7;      // 0..7
    const long brow = (long)mblk * BM;
    const int  bcol = jblk * BNJ;

    f32x4 acc[5][4][2];
#pragma unroll
    for (int g = 0; g < 5; ++g)
#pragma unroll
        for (int m = 0; m < 4; ++m)
#pragma unroll
            for (int jf = 0; jf < 2; ++jf)
#pragma unroll
                for (int r = 0; r < 4; ++r) acc[g][m][jf][r] = 0.f;

    bf16x8 afA[2][4];
    bf16x8 bs0[5], bs1[5];

    // ---- read-side LDS pointers (imm-offset addressable) ----
    const int aboff = (wm * 64 + fr) * 128;
    const int swz0  = ((q) ^ (fr & 7)) << 4;
    const int swz1  = ((4 | q) ^ (fr & 7)) << 4;
    const unsigned char* aP0k0 = lds_raw + aboff + swz0;
    const unsigned char* aP0k1 = lds_raw + aboff + swz1;
    const unsigned char* aP1k0 = aP0k0 + LDSB;
    const unsigned char* aP1k1 = aP0k1 + LDSB;
    const unsigned char* bP0 = lds_raw + 32768 + wj * 20480 + lane * 16;
    const unsigned char* bP1 = bP0 + LDSB;

    // ---- staging pointers ----
    const int r0_ = tid >> 3;
    const unsigned short* asrc = A + (brow + r0_) * 1024L
                                   + (((tid & 7) ^ (r0_ & 7)) << 3);
    const int adst = tid * 16;
    const int bdst = 32768 + wid * 5120 + lane * 16;
    const int c0_ = wid * 5;
    const unsigned short* bstg0 = Bp + (long)(jblk*4 + (c0_+0)/10)*81920 + (((c0_+0)%10)>>1)*16384 + ((c0_+0)&1)*512 + lane*8;
    const unsigned short* bstg1 = Bp + (long)(jblk*4 + (c0_+1)/10)*81920 + (((c0_+1)%10)>>1)*16384 + ((c0_+1)&1)*512 + lane*8;
    const unsigned short* bstg2 = Bp + (long)(jblk*4 + (c0_+2)/10)*81920 + (((c0_+2)%10)>>1)*16384 + ((c0_+2)&1)*512 + lane*8;
    const unsigned short* bstg3 = Bp + (long)(jblk*4 + (c0_+3)/10)*81920 + (((c0_+3)%10)>>1)*16384 + ((c0_+3)&1)*512 + lane*8;
    const unsigned short* bstg4 = Bp + (long)(jblk*4 + (c0_+4)/10)*81920 + (((c0_+4)%10)>>1)*16384 + ((c0_+4)&1)*512 + lane*8;

    // ---- prologue: stage tile 0 into buf0, full certify (one-time) ----
    SGB(0, 0);
    SGA(0, 0);
    WAITVM0();
    BARRIER();

    // ---- main loop: 16 tiles, buf = t&1, stage t+1 into buf^1 ----
    for (int t = 0; t < 14; t += 2) {
        TILE(aP0k0, aP0k1, bP0, LDSB, t,     1, 1);
        TILE(aP1k0, aP1k1, bP1, 0,    t + 1, 1, 1);
    }
    TILE(aP0k0, aP0k1, bP0, LDSB, 14, 1, 1);
    TILE(aP1k0, aP1k1, bP1, 0,    15, 0, 0);

    // ---------------- epilogue (fused, in-register) ----------------
    const long mbase = brow + wm * 64 + (q << 2);
#pragma unroll
    for (int jf = 0; jf < 2; ++jf) {
        const int j = bcol + wj * 32 + jf * 16 + fr;
        const float bi_ = bias[j];
        const float bf_ = bias[512 + j];
        const float bc_ = bias[1024 + j];
        const float bo_ = bias[1536 + j];
        const float be_ = bias[2048 + j];
#pragma unroll
        for (int m = 0; m < 4; ++m) {
#pragma unroll
            for (int r = 0; r < 4; ++r) {
                long row = mbase + m * 16 + r;
                float gi = acc[0][m][jf][r] + bi_;
                float gf = acc[1][m][jf][r] + bf_;
                float gc = acc[2][m][jf][r] + bc_;
                float go = acc[3][m][jf][r] + bo_;
                float ge = acc[4][m][jf][r] + be_;
                float iv = fast_sigmoid(gi);
                float fv = fast_sigmoid(gf);
                float gv = fast_tanh(gc);
                float ov = fast_sigmoid(go);
                float ef = __expf(fast_tanh(ge));
                float cp = c_prev[row * 512 + j];
                float cv = fv * cp + iv * gv;
                float hv = ov * fast_tanh(cv) * ef;
                out[row * 512 + j] = hv;
                out[(long)Bsz * 512 + row * 512 + j] = cv;
            }
        }
    }
}

extern "C" void kernel_launch(void* const* d_in, const int* in_sizes, int n_in,
                              void* d_out, int out_size, void* d_ws, size_t ws_size,
                              hipStream_t stream) {
    const float* x      = (const float*)d_in[0];
    const float* h_prev = (const float*)d_in[1];
    const float* c_prev = (const float*)d_in[2];
    const float* Wxi = (const float*)d_in[3];
    const float* bxi = (const float*)d_in[4];
    const float* Whi = (const float*)d_in[5];
    const float* bhi = (const float*)d_in[6];
    const float* Wxf = (const float*)d_in[7];
    const float* bxf = (const float*)d_in[8];
    const float* Whf = (const float*)d_in[9];
    const float* bhf = (const float*)d_in[10];
    const float* Wxc = (const float*)d_in[11];
    const float* bxc = (const float*)d_in[12];
    const float* Whc = (const float*)d_in[13];
    const float* bhc = (const float*)d_in[14];
    const float* Wxo = (const float*)d_in[15];
    const float* bxo = (const float*)d_in[16];
    const float* Who = (const float*)d_in[17];
    const float* bho = (const float*)d_in[18];
    const float* We  = (const float*)d_in[19];
    const float* be  = (const float*)d_in[20];

    unsigned short* Abf  = (unsigned short*)d_ws;                        // 33,554,432 B
    unsigned short* Bp   = (unsigned short*)((char*)d_ws + 33554432);    //  5,242,880 B
    float*          bias = (float*)((char*)d_ws + 33554432 + 5242880);   //     10,240 B

    pack_A<<<2048, 256, 0, stream>>>(x, h_prev, Abf);
    pack_B<<<1280, 256, 0, stream>>>(Wxi, Whi, Wxf, Whf, Wxc, Whc, Wxo, Who, We,
                                     bxi, bhi, bxf, bhf, bxc, bhc, bxo, bho, be,
                                     Bp, bias);
    xlstm_gemm<<<512, 512, 0, stream>>>(Abf, Bp, bias, c_prev, (float*)d_out);
}

// Round 6
// 124.006 us; speedup vs baseline: 1.5954x; 1.5954x over previous
//
#include <hip/hip_runtime.h>
#include <stdint.h>

#define Bsz 16384
#define Hh  512
#define Kd  1024      // I + H
#define BM  128       // M rows per workgroup
#define BNJ 32        // j columns per workgroup (x5 gates)
#define BK  64        // K per tile
#define NT  16        // K tiles

// LDS buffer: A 16KB + B 20KB = 36KB; two buffers = 72KB -> 2 wg/CU
#define LDSB 36864

typedef __attribute__((ext_vector_type(8))) short bf16x8;
typedef __attribute__((ext_vector_type(4))) float f32x4;
typedef __attribute__((ext_vector_type(8))) unsigned short u16x8;

__device__ __forceinline__ unsigned short f2bf(float f) {
    union { float f; unsigned u; } v; v.f = f;
    unsigned u = v.u;
    return (unsigned short)((u + 0x7fffu + ((u >> 16) & 1u)) >> 16);
}
__device__ __forceinline__ float fast_tanh(float x) {
    float e = __expf(2.f * x);
    return (e - 1.f) / (e + 1.f);
}
__device__ __forceinline__ float fast_sigmoid(float x) {
    return 1.f / (1.f + __expf(-x));
}

// ---------------- pack A = [x | h_prev] -> bf16 [16384][1024] ----------------
__global__ void pack_A(const float* __restrict__ x, const float* __restrict__ h,
                       unsigned short* __restrict__ A) {
    const long total = (long)Bsz * Kd / 8;
    for (long i = (long)blockIdx.x * blockDim.x + threadIdx.x; i < total;
         i += (long)gridDim.x * blockDim.x) {
        long row = i >> 7;
        int  col = ((int)(i & 127)) << 3;
        const float* src = (col < 512) ? (x + row * 512 + col)
                                       : (h + row * 512 + (col - 512));
        float4 f0 = *(const float4*)(src);
        float4 f1 = *(const float4*)(src + 4);
        u16x8 o;
        o[0]=f2bf(f0.x); o[1]=f2bf(f0.y); o[2]=f2bf(f0.z); o[3]=f2bf(f0.w);
        o[4]=f2bf(f1.x); o[5]=f2bf(f1.y); o[6]=f2bf(f1.z); o[7]=f2bf(f1.w);
        *(u16x8*)(A + (i << 3)) = o;
    }
}

// ---- pack B into fragment-linear layout ----
// elem addr = jgrp*81920 + g*16384 + kt*1024 + kh*512 + l*8 + e
//  = W[g][ j = jgrp*16 + (l&15) ][ k = kt*64 + kh*32 + (l>>4)*8 + e ]
__global__ void pack_B(const float* __restrict__ Wxi, const float* __restrict__ Whi,
                       const float* __restrict__ Wxf, const float* __restrict__ Whf,
                       const float* __restrict__ Wxc, const float* __restrict__ Whc,
                       const float* __restrict__ Wxo, const float* __restrict__ Who,
                       const float* __restrict__ We,
                       const float* __restrict__ bxi, const float* __restrict__ bhi,
                       const float* __restrict__ bxf, const float* __restrict__ bhf,
                       const float* __restrict__ bxc, const float* __restrict__ bhc,
                       const float* __restrict__ bxo, const float* __restrict__ bho,
                       const float* __restrict__ be,
                       unsigned short* __restrict__ Bp, float* __restrict__ bias) {
    const long id = (long)blockIdx.x * blockDim.x + threadIdx.x;  // 327680 total
    if (id < 327680) {
        int blk = (int)(id >> 6);
        int l   = (int)(id & 63);
        int kh  = blk & 1;
        int kt  = (blk >> 1) & 15;
        int rest = blk >> 5;
        int g    = rest % 5;
        int jgrp = rest / 5;
        int j  = jgrp * 16 + (l & 15);
        int k0 = kt * 64 + kh * 32 + ((l >> 4) << 3);
        const float* src;
        if (g == 4) {
            src = We + (long)j * 1024 + k0;
        } else {
            const float* Wx = (g == 0) ? Wxi : (g == 1) ? Wxf : (g == 2) ? Wxc : Wxo;
            const float* Wh = (g == 0) ? Whi : (g == 1) ? Whf : (g == 2) ? Whc : Who;
            src = (k0 < 512) ? (Wx + (long)j * 512 + k0)
                             : (Wh + (long)j * 512 + (k0 - 512));
        }
        float4 f0 = *(const float4*)(src);
        float4 f1 = *(const float4*)(src + 4);
        u16x8 o;
        o[0]=f2bf(f0.x); o[1]=f2bf(f0.y); o[2]=f2bf(f0.z); o[3]=f2bf(f0.w);
        o[4]=f2bf(f1.x); o[5]=f2bf(f1.y); o[6]=f2bf(f1.z); o[7]=f2bf(f1.w);
        *(u16x8*)(Bp + (long)blk * 512 + l * 8) = o;
    }
    if (id < 2560) {
        int row = (int)id;
        int g = row >> 9, j = row & 511;
        float b;
        if (g == 4) b = be[j];
        else {
            const float* bx = (g == 0) ? bxi : (g == 1) ? bxf : (g == 2) ? bxc : bxo;
            const float* bh = (g == 0) ? bhi : (g == 1) ? bhf : (g == 2) ? bhc : bho;
            b = bx[j] + bh[j];
        }
        bias[row] = b;
    }
}

// ---------------- fused GEMM (5-gate): 1 barrier/tile, 2 wg/CU ----------------
#define GL16(g, l) __builtin_amdgcn_global_load_lds( \
    (const __attribute__((address_space(1))) unsigned int*)(g), \
    (__attribute__((address_space(3))) unsigned int*)(l), 16, 0, 0)

#define WAITVM0()  asm volatile("s_waitcnt vmcnt(0)" ::: "memory")
#define LGKM_I(n)  asm volatile("s_waitcnt lgkmcnt(" #n ")" ::: "memory")
#define LGKM(n)    LGKM_I(n)
#define BARRIER()  asm volatile("s_barrier" ::: "memory")
#define SCHED0()   __builtin_amdgcn_sched_barrier(0)

#define MF(a, b, c) __builtin_amdgcn_mfma_f32_16x16x32_bf16(a, b, c, 0, 0, 0)

// ---- LDS reads ----
#define RDA(KH, APTR) do { \
    afA[KH][0] = *(const bf16x8*)((APTR) + 0 * 2048); \
    afA[KH][1] = *(const bf16x8*)((APTR) + 1 * 2048); \
    afA[KH][2] = *(const bf16x8*)((APTR) + 2 * 2048); \
    afA[KH][3] = *(const bf16x8*)((APTR) + 3 * 2048); \
} while (0)

#define RDB(SET, BPTR, KH) do { \
    SET[0] = *(const bf16x8*)((BPTR) + (0 + (KH)) * 1024); \
    SET[1] = *(const bf16x8*)((BPTR) + (2 + (KH)) * 1024); \
    SET[2] = *(const bf16x8*)((BPTR) + (4 + (KH)) * 1024); \
    SET[3] = *(const bf16x8*)((BPTR) + (6 + (KH)) * 1024); \
    SET[4] = *(const bf16x8*)((BPTR) + (8 + (KH)) * 1024); \
} while (0)

// ---- staging: 4 A-chunks + 5 B-chunks per thread per tile (exact, uniform) ----
#define SGA(SO, T) do { \
    GL16(asrc + 0 * 32768 + (T) * 64, lds_raw + (SO) + adst + 0 * 4096); \
    GL16(asrc + 1 * 32768 + (T) * 64, lds_raw + (SO) + adst + 1 * 4096); \
    GL16(asrc + 2 * 32768 + (T) * 64, lds_raw + (SO) + adst + 2 * 4096); \
    GL16(asrc + 3 * 32768 + (T) * 64, lds_raw + (SO) + adst + 3 * 4096); \
} while (0)

#define SGB(SO, T) do { \
    GL16(bsg0 + (T) * 1024, lds_raw + (SO) + bdo0); \
    GL16(bsg1 + (T) * 1024, lds_raw + (SO) + bdo1); \
    GL16(bsg2 + (T) * 1024, lds_raw + (SO) + bdo2); \
    GL16(bsg3 + (T) * 1024, lds_raw + (SO) + bdo3); \
    GL16(bsg4 + (T) * 1024, lds_raw + (SO) + bdo4); \
} while (0)

#define MFMA20(KH, BSET) do { \
    __builtin_amdgcn_s_setprio(1); \
    _Pragma("unroll") \
    for (int g_ = 0; g_ < 5; ++g_) { \
        acc[g_][0] = MF(afA[KH][0], BSET[g_], acc[g_][0]); \
        acc[g_][1] = MF(afA[KH][1], BSET[g_], acc[g_][1]); \
        acc[g_][2] = MF(afA[KH][2], BSET[g_], acc[g_][2]); \
        acc[g_][3] = MF(afA[KH][3], BSET[g_], acc[g_][3]); \
    } \
    __builtin_amdgcn_s_setprio(0); \
} while (0)

// One K-tile: issue staging early, 18 ds_reads, counted lgkm, 2x20 MFMA,
// one vmcnt(0)+barrier at the end. STG/SYNC control tail.
#define TILE(AP0, AP1, BPTR, SO, T, STG, SYNC) do { \
    if (STG) { SGB(SO, (T) + 1); SGA(SO, (T) + 1); } SCHED0(); \
    RDA(0, AP0); RDB(bq0, BPTR, 0); SCHED0(); \
    RDA(1, AP1); RDB(bq1, BPTR, 1); SCHED0(); \
    LGKM(9); SCHED0(); \
    MFMA20(0, bq0); SCHED0(); \
    LGKM(0); SCHED0(); \
    MFMA20(1, bq1); \
    if (SYNC) { WAITVM0(); BARRIER(); } \
} while (0)

__global__ __launch_bounds__(256, 2)
void xlstm_gemm(const unsigned short* __restrict__ A,
                const unsigned short* __restrict__ Bp,
                const float* __restrict__ bias,
                const float* __restrict__ c_prev,
                float* __restrict__ out) {
    __shared__ __align__(16) unsigned char lds_raw[2 * LDSB];  // 72 KB

    const int tid  = threadIdx.x;
    const int wid  = tid >> 6;
    const int lane = tid & 63;
    const int wm   = wid >> 1;    // 0..1 : M half (64 rows)
    const int wj   = wid & 1;     // 0..1 : j half (16 cols)
    const int fr   = lane & 15;
    const int q    = lane >> 4;

    // T1: bijective XCD swizzle (nwg = 2048, 2048 % 8 == 0)
    const int orig = blockIdx.x;
    const int wg   = (orig & 7) * 256 + (orig >> 3);
    const int mblk = wg >> 4;     // 0..127
    const int jblk = wg & 15;     // 0..15
    const long brow = (long)mblk * BM;
    const int  bcol = jblk * BNJ;

    f32x4 acc[5][4];
#pragma unroll
    for (int g = 0; g < 5; ++g)
#pragma unroll
        for (int m = 0; m < 4; ++m)
#pragma unroll
            for (int r = 0; r < 4; ++r) acc[g][m][r] = 0.f;

    bf16x8 afA[2][4];
    bf16x8 bq0[5], bq1[5];

    // ---- read-side LDS pointers ----
    const int aboff = (wm * 64 + fr) * 128;
    const int swz0  = ((q) ^ (fr & 7)) << 4;
    const int swz1  = ((4 | q) ^ (fr & 7)) << 4;
    const unsigned char* aP0k0 = lds_raw + aboff + swz0;
    const unsigned char* aP0k1 = lds_raw + aboff + swz1;
    const unsigned char* aP1k0 = aP0k0 + LDSB;
    const unsigned char* aP1k1 = aP0k1 + LDSB;
    const unsigned char* bP0 = lds_raw + 16384 + wj * 10240 + lane * 16;
    const unsigned char* bP1 = bP0 + LDSB;

    // ---- staging pointers ----
    // A: thread stages chunks c = tid + i*256 (i<4): row = c>>3, ch = c&7
    const int r0_ = tid >> 3;
    const unsigned short* asrc = A + (brow + r0_) * 1024L
                                   + (((tid & 7) ^ (r0_ & 7)) << 3);
    const int adst = tid * 16;
    // B: thread stages frags f = (tid>>6) + 4*i (i<5), lane l = tid&63
    const int f0_ = tid >> 6;
    const unsigned short *bsg0, *bsg1, *bsg2, *bsg3, *bsg4;
    int bdo0, bdo1, bdo2, bdo3, bdo4;
#define BSTG_INIT(i) do { \
    int f_ = f0_ + 4 * (i); int jl_ = f_ / 10; int rem_ = f_ - 10 * jl_; \
    bsg##i = Bp + (long)(jblk * 2 + jl_) * 81920 + (rem_ >> 1) * 16384 \
               + (rem_ & 1) * 512 + (tid & 63) * 8; \
    bdo##i = 16384 + jl_ * 10240 + rem_ * 1024 + (tid & 63) * 16; \
} while (0)
    BSTG_INIT(0); BSTG_INIT(1); BSTG_INIT(2); BSTG_INIT(3); BSTG_INIT(4);

    // ---- prologue: stage tile 0 into buf0, certify ----
    SGB(0, 0);
    SGA(0, 0);
    WAITVM0();
    BARRIER();

    // ---- main loop: tile t reads buf t&1, stages t+1 into buf^1 ----
    for (int t = 0; t < 14; t += 2) {
        TILE(aP0k0, aP0k1, bP0, LDSB, t,     1, 1);
        TILE(aP1k0, aP1k1, bP1, 0,    t + 1, 1, 1);
    }
    TILE(aP0k0, aP0k1, bP0, LDSB, 14, 1, 1);
    TILE(aP1k0, aP1k1, bP1, 0,    15, 0, 0);

    // ---------------- epilogue (fused, in-register) ----------------
    const int j = bcol + wj * 16 + fr;
    const float bi_ = bias[j];
    const float bf_ = bias[512 + j];
    const float bc_ = bias[1024 + j];
    const float bo_ = bias[1536 + j];
    const float be_ = bias[2048 + j];
    const long mbase = brow + wm * 64 + (q << 2);
#pragma unroll
    for (int m = 0; m < 4; ++m) {
#pragma unroll
        for (int r = 0; r < 4; ++r) {
            long row = mbase + m * 16 + r;
            float gi = acc[0][m][r] + bi_;
            float gf = acc[1][m][r] + bf_;
            float gc = acc[2][m][r] + bc_;
            float go = acc[3][m][r] + bo_;
            float ge = acc[4][m][r] + be_;
            float iv = fast_sigmoid(gi);
            float fv = fast_sigmoid(gf);
            float gv = fast_tanh(gc);
            float ov = fast_sigmoid(go);
            float ef = __expf(fast_tanh(ge));
            float cp = c_prev[row * 512 + j];
            float cv = fv * cp + iv * gv;
            float hv = ov * fast_tanh(cv) * ef;
            out[row * 512 + j] = hv;
            out[(long)Bsz * 512 + row * 512 + j] = cv;
        }
    }
}

extern "C" void kernel_launch(void* const* d_in, const int* in_sizes, int n_in,
                              void* d_out, int out_size, void* d_ws, size_t ws_size,
                              hipStream_t stream) {
    const float* x      = (const float*)d_in[0];
    const float* h_prev = (const float*)d_in[1];
    const float* c_prev = (const float*)d_in[2];
    const float* Wxi = (const float*)d_in[3];
    const float* bxi = (const float*)d_in[4];
    const float* Whi = (const float*)d_in[5];
    const float* bhi = (const float*)d_in[6];
    const float* Wxf = (const float*)d_in[7];
    const float* bxf = (const float*)d_in[8];
    const float* Whf = (const float*)d_in[9];
    const float* bhf = (const float*)d_in[10];
    const float* Wxc = (const float*)d_in[11];
    const float* bxc = (const float*)d_in[12];
    const float* Whc = (const float*)d_in[13];
    const float* bhc = (const float*)d_in[14];
    const float* Wxo = (const float*)d_in[15];
    const float* bxo = (const float*)d_in[16];
    const float* Who = (const float*)d_in[17];
    const float* bho = (const float*)d_in[18];
    const float* We  = (const float*)d_in[19];
    const float* be  = (const float*)d_in[20];

    unsigned short* Abf  = (unsigned short*)d_ws;                        // 33,554,432 B
    unsigned short* Bp   = (unsigned short*)((char*)d_ws + 33554432);    //  5,242,880 B
    float*          bias = (float*)((char*)d_ws + 33554432 + 5242880);   //     10,240 B

    pack_A<<<2048, 256, 0, stream>>>(x, h_prev, Abf);
    pack_B<<<1280, 256, 0, stream>>>(Wxi, Whi, Wxf, Whf, Wxc, Whc, Wxo, Who, We,
                                     bxi, bhi, bxf, bhf, bxc, bhc, bxo, bho, be,
                                     Bp, bias);
    xlstm_gemm<<<2048, 256, 0, stream>>>(Abf, Bp, bias, c_prev, (float*)d_out);
}